// Round 8
// baseline (775.878 us; speedup 1.0000x reference)
//
#include <hip/hip_runtime.h>
#include <math.h>

// Problem constants
constexpr int kB    = 64;
constexpr int kN    = 32;
constexpr int kDIN  = 128;
constexpr int kH    = 256;
constexpr int kG4   = 1024;   // 4*H
constexpr int kDOUT = 128;
constexpr int kBN   = 2048;   // B*N

typedef __attribute__((ext_vector_type(8))) short bf16x8;
typedef __attribute__((ext_vector_type(4))) float f32x4;

__device__ __forceinline__ float sigm(float x) {
    return 1.0f / (1.0f + expf(-x));
}

// fp32 -> bf16 bits, round-to-nearest-even
__device__ __forceinline__ short f2bf(float f) {
    union { float f; unsigned u; } v; v.f = f;
    unsigned r = v.u + 0x7fffu + ((v.u >> 16) & 1u);
    return (short)(r >> 16);
}
__device__ __forceinline__ float bf2f(short s) {
    union { unsigned u; float f; } v;
    v.u = ((unsigned)(unsigned short)s) << 16;
    return v.f;
}

// ---------------------------------------------------------------------------
// K0 prep (448 blocks, dim3(32,8)):
//   [0,64)    W_ih_f -> bf16   [64,128) W_ih_r -> bf16
//   [128,256) W_hh_f -> bf16   [256,384) W_hh_r -> bf16   (all [gate][k])
//   [384,448) transpose W_fc (128x512) -> WfcT [k][dout] fp32
// ---------------------------------------------------------------------------
__global__ __launch_bounds__(256) void prep_k(
    const float* __restrict__ Wihf, const float* __restrict__ Wihr,
    const float* __restrict__ Whhf, const float* __restrict__ Whhr,
    const float* __restrict__ Wfc,
    short* __restrict__ Wih_bf_f, short* __restrict__ Wih_bf_r,
    short* __restrict__ Whh_bf_f, short* __restrict__ Whh_bf_r,
    float* __restrict__ WfcT)
{
    const int bx  = blockIdx.x;
    const int tid = threadIdx.y * 32 + threadIdx.x;
    if (bx < 384) {
        const float* src; short* dst; int lb;
        if (bx < 64)       { src = Wihf; dst = Wih_bf_f; lb = bx; }
        else if (bx < 128) { src = Wihr; dst = Wih_bf_r; lb = bx - 64; }
        else if (bx < 256) { src = Whhf; dst = Whh_bf_f; lb = bx - 128; }
        else               { src = Whhr; dst = Whh_bf_r; lb = bx - 256; }
        const int b2 = lb * 2048 + tid * 8;
        #pragma unroll
        for (int j = 0; j < 8; ++j) dst[b2 + j] = f2bf(src[b2 + j]);
        return;
    }
    __shared__ float tile[32][33];
    const int t  = bx - 384;
    const int tilesX = 512 / 32;
    const int c0 = (t % tilesX) * 32;
    const int r0 = (t / tilesX) * 32;
    const int tx = threadIdx.x;
    const int ty = threadIdx.y;
    #pragma unroll
    for (int i = ty; i < 32; i += 8)
        tile[i][tx] = Wfc[(size_t)(r0 + i) * 512 + (c0 + tx)];
    __syncthreads();
    #pragma unroll
    for (int i = ty; i < 32; i += 8)
        WfcT[(size_t)(c0 + i) * 128 + (r0 + tx)] = tile[tx][i];
}

// ---------------------------------------------------------------------------
// K2: fused xW prologue + bidirectional LSTM recurrence, bf16 MFMA.
// Grid: 128 blocks = dir(2) x batch(64).  512 threads = 8 waves.
// __launch_bounds__(512,1): second arg is min BLOCKS/CU (CUDA semantics) --
// 1 block/CU -> 256-reg budget so the 64-reg acc + W-load pipeline fits
// WITHOUT scratch spill (R5-R7 all spilled at 64/128-reg budgets, and the
// scratch churn evicted W_hh from L2 -> 700+ MB HBM fetch).
// M=32 n-rows per block, uniform 32 steps, diag row n written at t==n.
// kt loops are `#pragma unroll 1` to cap in-flight W loads (8x16B = 32 regs).
// ---------------------------------------------------------------------------
__global__ __launch_bounds__(512, 1) void k2_lstm(
    const float* __restrict__ x,
    const float* __restrict__ mask,
    const short* __restrict__ Wih_bf_f, const short* __restrict__ Wih_bf_r,
    const short* __restrict__ Whh_bf_f, const short* __restrict__ Whh_bf_r,
    const float* __restrict__ b_f,  const float* __restrict__ b_r,
    float* __restrict__ y)
{
    constexpr int HP = 264;                    // padded h row (shorts)
    __shared__ short h_lds[2][kN][HP];         // 33 KB
    __shared__ short xw_lds[kN][kG4];          // 64 KB
    __shared__ float mask_lds[kN][33];         // 4.2 KB
    __shared__ short xa[kN][136];              // 8.5 KB

    const int tid  = threadIdx.x;
    const int wave = tid >> 6;                 // 0..7
    const int lane = tid & 63;
    const int quad = lane >> 4;
    const int l15  = lane & 15;

    const int dir = blockIdx.x >> 6;           // 0 fwd, 1 rev
    const int b   = blockIdx.x & 63;

    const short* __restrict__ Wih = dir ? Wih_bf_r : Wih_bf_f;
    const short* __restrict__ Whh = dir ? Whh_bf_r : Whh_bf_f;
    const float* __restrict__ bb  = dir ? b_r : b_f;

    // lane-variant bases; all tau/kt offsets are compile-time constants
    const int colw = wave * 32 + l15;                    // this lane's unit col
    const short* Wbase  = Whh + (size_t)colw * kH + quad * 8;
    const short* Wibase = Wih + (size_t)colw * kDIN + quad * 8;

    float bias[8];
    #pragma unroll
    for (int g = 0; g < 4; ++g)
        #pragma unroll
        for (int q = 0; q < 2; ++q)
            bias[g * 2 + q] = bb[g * kH + wave * 32 + q * 16 + l15];

    // ---- stage x (bf16) + mask into LDS; zero h buffer 0 ----
    {
        const float* xb = x + (size_t)b * (kN * kDIN);
        #pragma unroll
        for (int i = tid; i < kN * kDIN; i += 512)
            xa[i >> 7][i & 127] = f2bf(xb[i]);
        const float* mb = mask + (size_t)b * (kN * kN);
        #pragma unroll
        for (int i = tid; i < kN * kN; i += 512)
            mask_lds[i >> 5][i & 31] = mb[i];
    }
    for (int i = tid; i < kN * HP; i += 512) (&h_lds[0][0][0])[i] = 0;
    __syncthreads();

    // ---- prologue: xw = x @ W_ih^T  (M=32, N=1024, K=128) ----
    {
        f32x4 axw[2][8];
        #pragma unroll
        for (int mt = 0; mt < 2; ++mt)
            #pragma unroll
            for (int tau = 0; tau < 8; ++tau)
                #pragma unroll
                for (int r = 0; r < 4; ++r) axw[mt][tau][r] = 0.f;

        #pragma unroll 1
        for (int kt = 0; kt < 4; ++kt) {
            bf16x8 a0 = *(const bf16x8*)&xa[l15][kt * 32 + quad * 8];
            bf16x8 a1 = *(const bf16x8*)&xa[l15 + 16][kt * 32 + quad * 8];
            #pragma unroll
            for (int g = 0; g < 4; ++g)
                #pragma unroll
                for (int q = 0; q < 2; ++q) {
                    bf16x8 bf = *(const bf16x8*)(Wibase + g * (kH * kDIN)
                                                 + q * (16 * kDIN) + kt * 32);
                    axw[0][g * 2 + q] = __builtin_amdgcn_mfma_f32_16x16x32_bf16(
                        a0, bf, axw[0][g * 2 + q], 0, 0, 0);
                    axw[1][g * 2 + q] = __builtin_amdgcn_mfma_f32_16x16x32_bf16(
                        a1, bf, axw[1][g * 2 + q], 0, 0, 0);
                }
        }
        #pragma unroll
        for (int mt = 0; mt < 2; ++mt)
            #pragma unroll
            for (int g = 0; g < 4; ++g)
                #pragma unroll
                for (int q = 0; q < 2; ++q)
                    #pragma unroll
                    for (int r = 0; r < 4; ++r)
                        xw_lds[mt * 16 + quad * 4 + r]
                              [g * kH + wave * 32 + q * 16 + l15] =
                            f2bf(axw[mt][g * 2 + q][r]);
    }
    __syncthreads();

    // ---- recurrence ----
    float c[16];   // ci = mt*8 + q*4 + r
    #pragma unroll
    for (int i = 0; i < 16; ++i) c[i] = 0.f;

    int cur = 0;
    #pragma unroll 1
    for (int it = 0; it < kN; ++it) {
        const int t = dir ? (kN - 1 - it) : it;

        // init: acc[n, col] = mask[n][t] * xw[t][col] + bias[col]
        f32x4 acc[2][8];
        {
            float xwv[8];
            #pragma unroll
            for (int g = 0; g < 4; ++g)
                #pragma unroll
                for (int q = 0; q < 2; ++q)
                    xwv[g * 2 + q] =
                        bf2f(xw_lds[t][g * kH + wave * 32 + q * 16 + l15]);
            #pragma unroll
            for (int mt = 0; mt < 2; ++mt) {
                float mk[4];
                #pragma unroll
                for (int r = 0; r < 4; ++r)
                    mk[r] = mask_lds[mt * 16 + quad * 4 + r][t];
                #pragma unroll
                for (int tau = 0; tau < 8; ++tau)
                    #pragma unroll
                    for (int r = 0; r < 4; ++r)
                        acc[mt][tau][r] = fmaf(mk[r], xwv[tau], bias[tau]);
            }
        }

        // K loop: h (LDS) @ W_hh^T (L2 stream); unroll 1 caps in-flight loads
        #pragma unroll 1
        for (int kt = 0; kt < 8; ++kt) {
            bf16x8 a0 = *(const bf16x8*)&h_lds[cur][l15][kt * 32 + quad * 8];
            bf16x8 a1 = *(const bf16x8*)&h_lds[cur][l15 + 16][kt * 32 + quad * 8];
            #pragma unroll
            for (int g = 0; g < 4; ++g)
                #pragma unroll
                for (int q = 0; q < 2; ++q) {
                    bf16x8 bf = *(const bf16x8*)(Wbase + g * (kH * kH)
                                                 + q * (16 * kH) + kt * 32);
                    acc[0][g * 2 + q] = __builtin_amdgcn_mfma_f32_16x16x32_bf16(
                        a0, bf, acc[0][g * 2 + q], 0, 0, 0);
                    acc[1][g * 2 + q] = __builtin_amdgcn_mfma_f32_16x16x32_bf16(
                        a1, bf, acc[1][g * 2 + q], 0, 0, 0);
                }
        }

        // epilogue: lane owns units u = wave*32 + q*16 + l15 for 8 n-rows
        const int nxt = cur ^ 1;
        #pragma unroll
        for (int mt = 0; mt < 2; ++mt)
            #pragma unroll
            for (int q = 0; q < 2; ++q)
                #pragma unroll
                for (int r = 0; r < 4; ++r) {
                    const int n  = mt * 16 + quad * 4 + r;
                    const int u  = wave * 32 + q * 16 + l15;
                    const int ci = mt * 8 + q * 4 + r;
                    const float gI = acc[mt][0 + q][r];
                    const float gF = acc[mt][2 + q][r];
                    const float gG = acc[mt][4 + q][r];
                    const float gO = acc[mt][6 + q][r];
                    const float ct = sigm(gF) * c[ci] + sigm(gI) * tanhf(gG);
                    c[ci] = ct;
                    const float hn = sigm(gO) * tanhf(ct);
                    h_lds[nxt][n][u] = f2bf(hn);
                    if (n == t)
                        y[((size_t)(b * kN + n)) * (2 * kH) + dir * kH + u] = hn;
                }
        __syncthreads();
        cur = nxt;
    }
}

// ---------------------------------------------------------------------------
// K3: out = relu(y @ W_fc.T + b_fc).  WfcT[k][dout] pre-transposed, fp32.
// ---------------------------------------------------------------------------
__global__ __launch_bounds__(256) void k3_out(
    const float* __restrict__ y, const float* __restrict__ WfcT,
    const float* __restrict__ b_fc, float* __restrict__ out)
{
    __shared__ float ys[8 * 2 * kH];
    const int tid = threadIdx.x;
    const int r0  = blockIdx.x * 8;
    const int col = tid & 127;
    const int rh  = tid >> 7;

    for (int i = tid; i < 8 * 2 * kH / 4; i += 256)
        ((float4*)ys)[i] = ((const float4*)(y + (size_t)r0 * (2 * kH)))[i];
    __syncthreads();

    float acc[4] = {0.f, 0.f, 0.f, 0.f};
    #pragma unroll 4
    for (int k = 0; k < 2 * kH; ++k) {
        const float w = WfcT[(size_t)k * kDOUT + col];
        #pragma unroll
        for (int j = 0; j < 4; ++j)
            acc[j] = fmaf(ys[(rh * 4 + j) * (2 * kH) + k], w, acc[j]);
    }

    const float bias = b_fc[col];
    #pragma unroll
    for (int j = 0; j < 4; ++j) {
        const int row = r0 + rh * 4 + j;
        out[(size_t)row * kDOUT + col] = fmaxf(acc[j] + bias, 0.f);
    }
}

// ---------------------------------------------------------------------------
extern "C" void kernel_launch(void* const* d_in, const int* in_sizes, int n_in,
                              void* d_out, int out_size, void* d_ws, size_t ws_size,
                              hipStream_t stream) {
    const float* x      = (const float*)d_in[0];
    const float* mask   = (const float*)d_in[1];
    const float* W_ih_f = (const float*)d_in[2];
    const float* W_hh_f = (const float*)d_in[3];
    const float* b_f    = (const float*)d_in[4];
    const float* W_ih_r = (const float*)d_in[5];
    const float* W_hh_r = (const float*)d_in[6];
    const float* b_r    = (const float*)d_in[7];
    const float* W_fc   = (const float*)d_in[8];
    const float* b_fc   = (const float*)d_in[9];
    float* out = (float*)d_out;

    short* ws       = (short*)d_ws;
    short* Wih_bf_f = ws;                      // 1024*128 bf16
    short* Wih_bf_r = Wih_bf_f + 131072;
    short* Whh_bf_f = Wih_bf_r + 131072;       // 1024*256 bf16
    short* Whh_bf_r = Whh_bf_f + 262144;
    float* WfcT     = (float*)(Whh_bf_r + 262144);   // 512*128 f
    float* yb       = WfcT + 65536;            // 2048*512 f

    prep_k<<<448, dim3(32, 8), 0, stream>>>(
        W_ih_f, W_ih_r, W_hh_f, W_hh_r, W_fc,
        Wih_bf_f, Wih_bf_r, Whh_bf_f, Whh_bf_r, WfcT);

    k2_lstm<<<128, 512, 0, stream>>>(
        x, mask, Wih_bf_f, Wih_bf_r, Whh_bf_f, Whh_bf_r, b_f, b_r, yb);

    k3_out<<<kBN / 8, 256, 0, stream>>>(yb, WfcT, b_fc, out);
}

// Round 9
// 709.823 us; speedup vs baseline: 1.0931x; 1.0931x over previous
//
#include <hip/hip_runtime.h>
#include <math.h>

// Problem constants
constexpr int kB    = 64;
constexpr int kN    = 32;
constexpr int kDIN  = 128;
constexpr int kH    = 256;
constexpr int kG4   = 1024;   // 4*H
constexpr int kDOUT = 128;
constexpr int kBN   = 2048;   // B*N

typedef __attribute__((ext_vector_type(8))) short bf16x8;
typedef __attribute__((ext_vector_type(4))) float f32x4;

__device__ __forceinline__ float sigm(float x) {
    return 1.0f / (1.0f + expf(-x));
}

// fp32 -> bf16 bits, round-to-nearest-even
__device__ __forceinline__ short f2bf(float f) {
    union { float f; unsigned u; } v; v.f = f;
    unsigned r = v.u + 0x7fffu + ((v.u >> 16) & 1u);
    return (short)(r >> 16);
}

// async global->LDS, 16B per lane. LDS dest = wave-uniform base + lane*16.
__device__ __forceinline__ void gld_lds16(const void* g, void* l) {
    __builtin_amdgcn_global_load_lds(
        (__attribute__((address_space(1))) void*)(g),
        (__attribute__((address_space(3))) void*)(l),
        16, 0, 0);
}

// ---------------------------------------------------------------------------
// K0 prep (448 blocks, dim3(32,8)):
//   [0,64)    W_ih_f -> bf16   [64,128) W_ih_r -> bf16
//   [128,256) W_hh_f -> bf16   [256,384) W_hh_r -> bf16   (all [gate][k])
//   [384,448) transpose W_fc (128x512) -> WfcT [k][dout] fp32
// ---------------------------------------------------------------------------
__global__ __launch_bounds__(256) void prep_k(
    const float* __restrict__ Wihf, const float* __restrict__ Wihr,
    const float* __restrict__ Whhf, const float* __restrict__ Whhr,
    const float* __restrict__ Wfc,
    short* __restrict__ Wih_bf_f, short* __restrict__ Wih_bf_r,
    short* __restrict__ Whh_bf_f, short* __restrict__ Whh_bf_r,
    float* __restrict__ WfcT)
{
    const int bx  = blockIdx.x;
    const int tid = threadIdx.y * 32 + threadIdx.x;
    if (bx < 384) {
        const float* src; short* dst; int lb;
        if (bx < 64)       { src = Wihf; dst = Wih_bf_f; lb = bx; }
        else if (bx < 128) { src = Wihr; dst = Wih_bf_r; lb = bx - 64; }
        else if (bx < 256) { src = Whhf; dst = Whh_bf_f; lb = bx - 128; }
        else               { src = Whhr; dst = Whh_bf_r; lb = bx - 256; }
        const int b2 = lb * 2048 + tid * 8;
        #pragma unroll
        for (int j = 0; j < 8; ++j) dst[b2 + j] = f2bf(src[b2 + j]);
        return;
    }
    __shared__ float tile[32][33];
    const int t  = bx - 384;
    const int tilesX = 512 / 32;
    const int c0 = (t % tilesX) * 32;
    const int r0 = (t / tilesX) * 32;
    const int tx = threadIdx.x;
    const int ty = threadIdx.y;
    #pragma unroll
    for (int i = ty; i < 32; i += 8)
        tile[i][tx] = Wfc[(size_t)(r0 + i) * 512 + (c0 + tx)];
    __syncthreads();
    #pragma unroll
    for (int i = ty; i < 32; i += 8)
        WfcT[(size_t)(c0 + i) * 128 + (r0 + tx)] = tile[tx][i];
}

// ---------------------------------------------------------------------------
// K2: fused xW prologue + bidirectional LSTM recurrence, bf16 MFMA.
// Grid: 128 blocks = dir(2) x batch(64).  512 threads = 8 waves, (512,1).
// M=32 n-rows, uniform 32 steps, diag row n written at t==n.
// W_hh is NOT read via scattered VMEM in the K-loop (R3-R8 bottleneck).
// Instead: 16 chunks/step (p=64k x g=256cols, 32 KB), double-buffered in
// LDS, staged with coalesced width-16 global_load_lds by all 8 waves.
// LDS chunk layout [col][k] (128B/col) with XOR swizzle slot = k16 ^ (col&7)
// so B-frag ds_read_b128 is <=2-way bank aliasing (free).
// xw (32x1024 fp32) lives in global scratch; row t prefetched a step ahead.
// h single-buffered (A-reads end at chunk 12; epilogue after chunk 15).
// ---------------------------------------------------------------------------
__global__ __launch_bounds__(512, 1) void k2_lstm(
    const float* __restrict__ x,
    const float* __restrict__ mask,
    const short* __restrict__ Wih_bf_f, const short* __restrict__ Wih_bf_r,
    const short* __restrict__ Whh_bf_f, const short* __restrict__ Whh_bf_r,
    const float* __restrict__ b_f,  const float* __restrict__ b_r,
    float* __restrict__ xw_ws,
    float* __restrict__ y)
{
    constexpr int HP = 264;                       // padded h row (shorts)
    __shared__ __align__(16) short h_lds[kN][HP]; // 16.5 KB
    __shared__ __align__(16) short wbuf[2][16384];// 64 KB (2 x 32 KB chunks)
    __shared__ float mask_lds[kN][33];            // 4.2 KB

    const int tid  = threadIdx.x;
    const int wave = tid >> 6;                 // 0..7
    const int lane = tid & 63;
    const int quad = lane >> 4;
    const int l15  = lane & 15;
    const int sw   = l15 & 7;

    const int dir = blockIdx.x >> 6;           // 0 fwd, 1 rev
    const int b   = blockIdx.x & 63;

    const short* __restrict__ Wih = dir ? Wih_bf_r : Wih_bf_f;
    const short* __restrict__ Whh = dir ? Whh_bf_r : Whh_bf_f;
    const float* __restrict__ bb  = dir ? b_r : b_f;
    float* __restrict__ xwg = xw_ws + (size_t)blockIdx.x * (kN * kG4);

    // gate-col bases: tau = g*2+q
    int nb[8];
    #pragma unroll
    for (int g = 0; g < 4; ++g)
        #pragma unroll
        for (int q = 0; q < 2; ++q)
            nb[g * 2 + q] = g * kH + wave * 32 + q * 16;

    float bias[8];
    #pragma unroll
    for (int tau = 0; tau < 8; ++tau) bias[tau] = bb[nb[tau] + l15];

    // staging per-lane invariants (4 x 16B segments per chunk per lane)
    int seg_off[4], lds_off[4];
    #pragma unroll
    for (int j = 0; j < 4; ++j) {
        const int s   = (wave * 4 + j) * 64 + lane;   // 0..2047
        const int col = s >> 3;
        const int k16 = (s & 7) ^ (col & 7);
        seg_off[j] = col * kH + k16 * 8;              // elements (shorts)
        lds_off[j] = (wave * 4 + j) * 512;            // shorts
    }

    // B-frag per-lane LDS offsets (shorts)
    int cb[2];
    #pragma unroll
    for (int q = 0; q < 2; ++q) cb[q] = (wave * 32 + q * 16 + l15) * 64;
    int ko[2];
    ko[0] = (quad ^ sw) * 8;
    ko[1] = ((4 | quad) ^ sw) * 8;

    // ---- stage x (bf16, aliased into wbuf[0]) + mask; zero h ----
    short (*xa)[kDIN] = (short (*)[kDIN])(&wbuf[0][0]);
    {
        const float* xb = x + (size_t)b * (kN * kDIN);
        for (int i = tid; i < kN * kDIN; i += 512)
            xa[i >> 7][i & 127] = f2bf(xb[i]);
        const float* mb = mask + (size_t)b * (kN * kN);
        for (int i = tid; i < kN * kN; i += 512)
            mask_lds[i >> 5][i & 31] = mb[i];
        for (int i = tid; i < kN * HP; i += 512) (&h_lds[0][0])[i] = 0;
    }
    __syncthreads();

    // ---- prologue: xw = x @ W_ih^T  -> global xwg (fp32) ----
    {
        const short* Wibase = Wih + (size_t)(wave * 32 + l15) * kDIN + quad * 8;
        f32x4 axw[2][8];
        #pragma unroll
        for (int mt = 0; mt < 2; ++mt)
            #pragma unroll
            for (int tau = 0; tau < 8; ++tau)
                #pragma unroll
                for (int r = 0; r < 4; ++r) axw[mt][tau][r] = 0.f;

        #pragma unroll 1
        for (int kt = 0; kt < 4; ++kt) {
            bf16x8 a0 = *(const bf16x8*)&xa[l15][kt * 32 + quad * 8];
            bf16x8 a1 = *(const bf16x8*)&xa[l15 + 16][kt * 32 + quad * 8];
            #pragma unroll
            for (int g = 0; g < 4; ++g)
                #pragma unroll
                for (int q = 0; q < 2; ++q) {
                    bf16x8 bf = *(const bf16x8*)(Wibase + g * (kH * kDIN)
                                                 + q * (16 * kDIN) + kt * 32);
                    axw[0][g * 2 + q] = __builtin_amdgcn_mfma_f32_16x16x32_bf16(
                        a0, bf, axw[0][g * 2 + q], 0, 0, 0);
                    axw[1][g * 2 + q] = __builtin_amdgcn_mfma_f32_16x16x32_bf16(
                        a1, bf, axw[1][g * 2 + q], 0, 0, 0);
                }
        }
        #pragma unroll
        for (int mt = 0; mt < 2; ++mt)
            #pragma unroll
            for (int g = 0; g < 4; ++g)
                #pragma unroll
                for (int q = 0; q < 2; ++q)
                    #pragma unroll
                    for (int r = 0; r < 4; ++r)
                        xwg[(size_t)(mt * 16 + quad * 4 + r) * kG4
                            + g * kH + wave * 32 + q * 16 + l15] =
                            axw[mt][g * 2 + q][r];
    }
    __syncthreads();   // xwg visible; wbuf[0] free for W chunks

    // ---- initial staging: chunk 0 (p=0,g=0) -> buf 0 ----
    #pragma unroll
    for (int j = 0; j < 4; ++j)
        gld_lds16(Whh + seg_off[j], &wbuf[0][lds_off[j]]);

    // ---- initial xw-row prefetch ----
    const int t0 = dir ? (kN - 1) : 0;
    float xwn[8];
    {
        const float* xr = xwg + (size_t)t0 * kG4;
        #pragma unroll
        for (int tau = 0; tau < 8; ++tau) xwn[tau] = xr[nb[tau] + l15];
    }

    float c[16];
    #pragma unroll
    for (int i = 0; i < 16; ++i) c[i] = 0.f;

    // ---- recurrence ----
    #pragma unroll 1
    for (int it = 0; it < kN; ++it) {
        const int t  = dir ? (kN - 1 - it) : it;
        const int tn = (it + 1 < kN) ? (dir ? t - 1 : t + 1) : t;

        // acc init from prefetched xw row + mask
        f32x4 acc[2][8];
        #pragma unroll
        for (int mt = 0; mt < 2; ++mt) {
            float mk[4];
            #pragma unroll
            for (int r = 0; r < 4; ++r)
                mk[r] = mask_lds[mt * 16 + quad * 4 + r][t];
            #pragma unroll
            for (int tau = 0; tau < 8; ++tau)
                #pragma unroll
                for (int r = 0; r < 4; ++r)
                    acc[mt][tau][r] = fmaf(mk[r], xwn[tau], bias[tau]);
        }
        // prefetch next step's xw row (drains at an early chunk barrier)
        {
            const float* xr = xwg + (size_t)tn * kG4;
            #pragma unroll
            for (int tau = 0; tau < 8; ++tau) xwn[tau] = xr[nb[tau] + l15];
        }

        bf16x8 a[2][2];   // [kt_local][mt], refreshed per p
        #pragma unroll
        for (int p = 0; p < 4; ++p) {
            #pragma unroll
            for (int g = 0; g < 4; ++g) {
                const int ci  = p * 4 + g;
                const int nci = (ci + 1) & 15;
                __syncthreads();   // drains staging of chunk ci (+ prefetch)

                // stage chunk ci+1 into the other buffer
                {
                    const int np = nci >> 2, ng = nci & 3;
                    const short* gbase = Whh + (size_t)(ng * 256) * kH + np * 64;
                    short* lbase = &wbuf[(ci + 1) & 1][0];
                    #pragma unroll
                    for (int j = 0; j < 4; ++j)
                        gld_lds16(gbase + seg_off[j], lbase + lds_off[j]);
                }

                if (g == 0) {
                    #pragma unroll
                    for (int kl = 0; kl < 2; ++kl)
                        #pragma unroll
                        for (int mt = 0; mt < 2; ++mt)
                            a[kl][mt] = *(const bf16x8*)
                                &h_lds[mt * 16 + l15][p * 64 + kl * 32 + quad * 8];
                }

                // compute chunk ci from wbuf[ci&1]
                const short* wb = &wbuf[ci & 1][0];
                #pragma unroll
                for (int kl = 0; kl < 2; ++kl)
                    #pragma unroll
                    for (int q = 0; q < 2; ++q) {
                        bf16x8 bf = *(const bf16x8*)(wb + cb[q] + ko[kl]);
                        acc[0][g * 2 + q] = __builtin_amdgcn_mfma_f32_16x16x32_bf16(
                            a[kl][0], bf, acc[0][g * 2 + q], 0, 0, 0);
                        acc[1][g * 2 + q] = __builtin_amdgcn_mfma_f32_16x16x32_bf16(
                            a[kl][1], bf, acc[1][g * 2 + q], 0, 0, 0);
                    }
            }
        }

        // epilogue: lane owns units u = wave*32 + q*16 + l15 for 8 n-rows
        #pragma unroll
        for (int mt = 0; mt < 2; ++mt)
            #pragma unroll
            for (int q = 0; q < 2; ++q)
                #pragma unroll
                for (int r = 0; r < 4; ++r) {
                    const int n  = mt * 16 + quad * 4 + r;
                    const int u  = wave * 32 + q * 16 + l15;
                    const int ci = mt * 8 + q * 4 + r;
                    const float gI = acc[mt][0 + q][r];
                    const float gF = acc[mt][2 + q][r];
                    const float gG = acc[mt][4 + q][r];
                    const float gO = acc[mt][6 + q][r];
                    const float ct = sigm(gF) * c[ci] + sigm(gI) * tanhf(gG);
                    c[ci] = ct;
                    const float hn = sigm(gO) * tanhf(ct);
                    h_lds[n][u] = f2bf(hn);
                    if (n == t)
                        y[((size_t)(b * kN + n)) * (2 * kH) + dir * kH + u] = hn;
                }
    }
    __syncthreads();   // drain trailing staged chunk before endpgm
}

// ---------------------------------------------------------------------------
// K3: out = relu(y @ W_fc.T + b_fc).  WfcT[k][dout] pre-transposed, fp32.
// ---------------------------------------------------------------------------
__global__ __launch_bounds__(256) void k3_out(
    const float* __restrict__ y, const float* __restrict__ WfcT,
    const float* __restrict__ b_fc, float* __restrict__ out)
{
    __shared__ float ys[8 * 2 * kH];
    const int tid = threadIdx.x;
    const int r0  = blockIdx.x * 8;
    const int col = tid & 127;
    const int rh  = tid >> 7;

    for (int i = tid; i < 8 * 2 * kH / 4; i += 256)
        ((float4*)ys)[i] = ((const float4*)(y + (size_t)r0 * (2 * kH)))[i];
    __syncthreads();

    float acc[4] = {0.f, 0.f, 0.f, 0.f};
    #pragma unroll 4
    for (int k = 0; k < 2 * kH; ++k) {
        const float w = WfcT[(size_t)k * kDOUT + col];
        #pragma unroll
        for (int j = 0; j < 4; ++j)
            acc[j] = fmaf(ys[(rh * 4 + j) * (2 * kH) + k], w, acc[j]);
    }

    const float bias = b_fc[col];
    #pragma unroll
    for (int j = 0; j < 4; ++j) {
        const int row = r0 + rh * 4 + j;
        out[(size_t)row * kDOUT + col] = fmaxf(acc[j] + bias, 0.f);
    }
}

// ---------------------------------------------------------------------------
extern "C" void kernel_launch(void* const* d_in, const int* in_sizes, int n_in,
                              void* d_out, int out_size, void* d_ws, size_t ws_size,
                              hipStream_t stream) {
    const float* x      = (const float*)d_in[0];
    const float* mask   = (const float*)d_in[1];
    const float* W_ih_f = (const float*)d_in[2];
    const float* W_hh_f = (const float*)d_in[3];
    const float* b_f    = (const float*)d_in[4];
    const float* W_ih_r = (const float*)d_in[5];
    const float* W_hh_r = (const float*)d_in[6];
    const float* b_r    = (const float*)d_in[7];
    const float* W_fc   = (const float*)d_in[8];
    const float* b_fc   = (const float*)d_in[9];
    float* out = (float*)d_out;

    short* ws       = (short*)d_ws;
    short* Wih_bf_f = ws;                      // 1024*128 bf16
    short* Wih_bf_r = Wih_bf_f + 131072;
    short* Whh_bf_f = Wih_bf_r + 131072;       // 1024*256 bf16
    short* Whh_bf_r = Whh_bf_f + 262144;
    float* WfcT     = (float*)(Whh_bf_r + 262144);   // 512*128 f
    float* yb       = WfcT + 65536;            // 2048*512 f
    float* xw_ws    = yb + 1048576;            // 128 * 32 * 1024 f (16 MB)

    prep_k<<<448, dim3(32, 8), 0, stream>>>(
        W_ih_f, W_ih_r, W_hh_f, W_hh_r, W_fc,
        Wih_bf_f, Wih_bf_r, Whh_bf_f, Whh_bf_r, WfcT);

    k2_lstm<<<128, 512, 0, stream>>>(
        x, mask, Wih_bf_f, Wih_bf_r, Whh_bf_f, Whh_bf_r, b_f, b_r, xw_ws, yb);

    k3_out<<<kBN / 8, 256, 0, stream>>>(yb, WfcT, b_fc, out);
}